// Round 11
// baseline (479.739 us; speedup 1.0000x reference)
//
#include <hip/hip_runtime.h>

#define N_NODES 100000
#define NE      1600000
#define C       128
#define NB      98        // buckets of 1024 destination nodes
#define BCAP    20480     // per-bucket capacity; mean 16384, ~32-sigma margin
#define EPB     2048      // edges per binA block

typedef __attribute__((ext_vector_type(8))) short short8;
typedef __attribute__((ext_vector_type(4))) float float4v;

__device__ __forceinline__ unsigned short bf16rne(float f) {
    unsigned int u = __float_as_uint(f);
    return (unsigned short)((u + 0x7FFFu + ((u >> 16) & 1u)) >> 16);
}
__device__ __forceinline__ float blo(unsigned int u) { return __uint_as_float(u << 16); }
__device__ __forceinline__ float bhi(unsigned int u) { return __uint_as_float(u & 0xFFFF0000u); }

// ---- binA: coarse-bucket by c>>10 with LDS-staged coalesced writes --------
__global__ __launch_bounds__(256) void binA_kernel(const int* __restrict__ row,
                                                   const int* __restrict__ col,
                                                   const float* __restrict__ ew,
                                                   int* __restrict__ gbcur,
                                                   uint2* __restrict__ babuf) {
    __shared__ int   hcnt[NB];
    __shared__ int   hofs[NB];
    __shared__ int   hbase[NB];
    __shared__ int   lofs[NB];
    __shared__ uint2 recs[EPB];   // 16 KB
    __shared__ int   gdst[EPB];   // 8 KB
    const int t = threadIdx.x;
    for (int i = t; i < NB; i += 256) { hcnt[i] = 0; hofs[i] = 0; }
    __syncthreads();

    const int e0 = blockIdx.x * EPB;
    int cc[8], rr[8]; float ee[8];
#pragma unroll
    for (int i = 0; i < 8; i++) {
        int e = e0 + i * 256 + t;
        if (e < NE) { cc[i] = col[e]; rr[i] = row[e]; ee[i] = ew[e]; }
        else cc[i] = -1;
    }
#pragma unroll
    for (int i = 0; i < 8; i++)
        if (cc[i] >= 0) atomicAdd(&hcnt[cc[i] >> 10], 1);
    __syncthreads();
    if (t < NB) {
        int c = hcnt[t];
        hbase[t] = c ? atomicAdd(&gbcur[t], c) : 0;
    }
    if (t == 0) {
        int run = 0;
        for (int b = 0; b < NB; b++) { lofs[b] = run; run += hcnt[b]; }
    }
    __syncthreads();
#pragma unroll
    for (int i = 0; i < 8; i++) {
        if (cc[i] < 0) continue;
        int b = cc[i] >> 10;
        int lpos = atomicAdd(&hofs[b], 1);
        int si = lofs[b] + lpos;
        unsigned int meta = ((unsigned int)(cc[i] & 1023) << 17) | (unsigned int)rr[i];
        recs[si] = make_uint2(meta, __float_as_uint(ee[i]));
        int gp = hbase[b] + lpos;
        gdst[si] = (gp < BCAP) ? (b * BCAP + gp) : -1;
    }
    __syncthreads();
    const int valid = lofs[NB - 1] + hcnt[NB - 1];
    for (int i = t; i < valid; i += 256) {
        int g = gdst[i];
        if (g >= 0) babuf[g] = recs[i];
    }
}

// ---- binB: per-bucket histogram + weighted degree + scan + local scatter --
__global__ __launch_bounds__(256) void binB_kernel(const int* __restrict__ gbcur,
                                                   const uint2* __restrict__ babuf,
                                                   float* __restrict__ dinv,
                                                   uint2* __restrict__ cursor2,
                                                   uint2* __restrict__ sedge) {
    __shared__ int   cnt[1024];
    __shared__ float deg[1024];
    __shared__ int   ofs[1024];
    __shared__ int   tsum[256];
    const int b = blockIdx.x, t = threadIdx.x;
    const int n0 = b << 10;
    const int nn = min(1024, N_NODES - n0);

    for (int i = t; i < 1024; i += 256) { cnt[i] = 0; deg[i] = 0.f; }
    __syncthreads();

    const int msize = min(gbcur[b], BCAP);
    const uint2* bb = babuf + (size_t)b * BCAP;
    for (int i = t; i < msize; i += 256) {
        uint2 m = bb[i];
        int cl = m.x >> 17;
        atomicAdd(&cnt[cl], 1);
        atomicAdd(&deg[cl], __uint_as_float(m.y));
    }
    __syncthreads();

    for (int i = t; i < nn; i += 256)
        dinv[n0 + i] = 1.0f / sqrtf(deg[i] + 1.0f);

    const int b4 = t * 4;
    int c0 = cnt[b4], c1 = cnt[b4 + 1], c2 = cnt[b4 + 2], c3 = cnt[b4 + 3];
    tsum[t] = c0 + c1 + c2 + c3;
    __syncthreads();
    for (int off = 1; off < 256; off <<= 1) {
        int v = (t >= off) ? tsum[t - off] : 0;
        __syncthreads();
        tsum[t] += v;
        __syncthreads();
    }
    int texcl = t ? tsum[t - 1] : 0;
    ofs[b4]     = texcl;
    ofs[b4 + 1] = texcl + c0;
    ofs[b4 + 2] = texcl + c0 + c1;
    ofs[b4 + 3] = texcl + c0 + c1 + c2;
    __syncthreads();

    const unsigned int ebase = (unsigned int)b * BCAP;
    for (int i = t; i < nn; i += 256) {
        unsigned int st = ebase + (unsigned int)ofs[i];
        cursor2[n0 + i] = make_uint2(st, st + (unsigned int)cnt[i]);
    }
    __syncthreads();

    for (int i = t; i < msize; i += 256) {
        uint2 m = bb[i];
        int cl = m.x >> 17;
        int p = atomicAdd(&ofs[cl], 1);
        sedge[(size_t)b * BCAP + p] = make_uint2(m.x & 0x1FFFFu, m.y);
    }
}

// ---- Wt[l][n][k] = bf16(Wl[k][n]) for all 3 layers in one dispatch --------
__global__ __launch_bounds__(256) void wt3_kernel(const float* __restrict__ W1,
                                                  const float* __restrict__ W2,
                                                  const float* __restrict__ W3,
                                                  unsigned short* __restrict__ Wt) {
    int layer = blockIdx.y;
    const float* W = layer == 0 ? W1 : (layer == 1 ? W2 : W3);
    int i = blockIdx.x * 256 + threadIdx.x;   // 16384 per layer
    int n = i >> 7, k = i & 127;
    Wt[layer * 16384 + i] = bf16rne(W[k * 128 + n]);
}

// ---------------- MFMA GEMM, LDS-free: T = bf16( dinv * (X @ W) ) ----------
// One wave handles 16 rows x 128 cols; 4 waves/block, 64 rows/block.
// A fragment = 16 contiguous bytes of the input row (direct global load,
// fp32->bf16 in-register for layer 1); B fragment = direct load from Wt[n][k]
// (identical addresses across blocks -> L2 broadcast). No LDS, no barriers.
__global__ __launch_bounds__(256) void gemm_mfma(const float* __restrict__ Xf,
                                                 const unsigned short* __restrict__ Xb,
                                                 const unsigned short* __restrict__ Wt,
                                                 const float* __restrict__ dinv,
                                                 unsigned short* __restrict__ Yb,
                                                 int n) {
    const int wave = threadIdx.x >> 6, lane = threadIdx.x & 63;
    const int m = lane & 15, quad = lane >> 4;
    const int gra = blockIdx.x * 64 + wave * 16 + m;   // row of this lane's A frag

    float4v acc[8];
#pragma unroll
    for (int t = 0; t < 8; t++) acc[t] = (float4v){0.f, 0.f, 0.f, 0.f};

#pragma unroll
    for (int kc = 0; kc < 4; kc++) {
        const int k0 = kc * 32 + quad * 8;
        short8 a = (short8){0, 0, 0, 0, 0, 0, 0, 0};
        if (gra < n) {
            if (Xf) {
                float4 f0 = *(const float4*)(Xf + (size_t)gra * 128 + k0);
                float4 f1 = *(const float4*)(Xf + (size_t)gra * 128 + k0 + 4);
                a[0] = (short)bf16rne(f0.x); a[1] = (short)bf16rne(f0.y);
                a[2] = (short)bf16rne(f0.z); a[3] = (short)bf16rne(f0.w);
                a[4] = (short)bf16rne(f1.x); a[5] = (short)bf16rne(f1.y);
                a[6] = (short)bf16rne(f1.z); a[7] = (short)bf16rne(f1.w);
            } else {
                a = *(const short8*)(Xb + (size_t)gra * 128 + k0);
            }
        }
#pragma unroll
        for (int t = 0; t < 8; t++) {
            short8 b = *(const short8*)(Wt + (t * 16 + m) * 128 + k0);
            acc[t] = __builtin_amdgcn_mfma_f32_16x16x32_bf16(a, b, acc[t], 0, 0, 0);
        }
    }
    // C/D layout: col = t*16 + m, row = quad*4 + r (within wave's 16 rows)
    float dv[4];
#pragma unroll
    for (int r = 0; r < 4; r++) {
        int gr = blockIdx.x * 64 + wave * 16 + quad * 4 + r;
        dv[r] = (gr < n) ? dinv[gr] : 0.f;
    }
#pragma unroll
    for (int t = 0; t < 8; t++) {
#pragma unroll
        for (int r = 0; r < 4; r++) {
            int gr = blockIdx.x * 64 + wave * 16 + quad * 4 + r;
            if (gr < n) Yb[(size_t)gr * 128 + t * 16 + m] = bf16rne(acc[t][r] * dv[r]);
        }
    }
}

// -------- CSR gather: h = relu( dinv[c]*(T[c] + sum ew*T[r]) + bias ) ------
// 16 lanes per node (16 nodes/block), 16B dwordx4 per lane per edge.
// If outp != nullptr: fuse final linear (dot with lw, +lb) instead of h.
__global__ __launch_bounds__(256) void gather_csr(const uint2* __restrict__ cursor2,
                                                  const uint2* __restrict__ sedge,
                                                  const unsigned short* __restrict__ xwb,
                                                  const float* __restrict__ dinv,
                                                  const float* __restrict__ bias,
                                                  unsigned short* __restrict__ hb,
                                                  float* __restrict__ outp,
                                                  const float* __restrict__ lw,
                                                  const float* __restrict__ lb) {
    int node = blockIdx.x * 16 + (threadIdx.x >> 4);
    int lane = threadIdx.x & 15;
    if (node >= N_NODES) return;
    uint2 cu = cursor2[node];
    int e = (int)cu.x, end = (int)cu.y;
    const uint4* tab = (const uint4*)xwb;   // 16 uint4 per node row

    uint4 q0 = tab[(size_t)node * 16 + lane];
    float4 aL, aH;
    aL.x = blo(q0.x); aL.y = bhi(q0.x); aL.z = blo(q0.y); aL.w = bhi(q0.y);
    aH.x = blo(q0.z); aH.y = bhi(q0.z); aH.z = blo(q0.w); aH.w = bhi(q0.w);

    for (; e + 4 <= end; e += 4) {
        uint2 E[4]; uint4 q[4];
#pragma unroll
        for (int j = 0; j < 4; j++) E[j] = sedge[e + j];
#pragma unroll
        for (int j = 0; j < 4; j++) q[j] = tab[(size_t)E[j].x * 16 + lane];
#pragma unroll
        for (int j = 0; j < 4; j++) {
            float w = __uint_as_float(E[j].y);
            aL.x += w * blo(q[j].x); aL.y += w * bhi(q[j].x);
            aL.z += w * blo(q[j].y); aL.w += w * bhi(q[j].y);
            aH.x += w * blo(q[j].z); aH.y += w * bhi(q[j].z);
            aH.z += w * blo(q[j].w); aH.w += w * bhi(q[j].w);
        }
    }
    for (; e < end; ++e) {
        uint2 E = sedge[e];
        float w = __uint_as_float(E.y);
        uint4 q = tab[(size_t)E.x * 16 + lane];
        aL.x += w * blo(q.x); aL.y += w * bhi(q.x);
        aL.z += w * blo(q.y); aL.w += w * bhi(q.y);
        aH.x += w * blo(q.z); aH.y += w * bhi(q.z);
        aH.z += w * blo(q.w); aH.w += w * bhi(q.w);
    }

    float d = dinv[node];
    float4 b0 = ((const float4*)bias)[lane * 2];
    float4 b1 = ((const float4*)bias)[lane * 2 + 1];
    aL.x = fmaxf(fmaf(d, aL.x, b0.x), 0.f);
    aL.y = fmaxf(fmaf(d, aL.y, b0.y), 0.f);
    aL.z = fmaxf(fmaf(d, aL.z, b0.z), 0.f);
    aL.w = fmaxf(fmaf(d, aL.w, b0.w), 0.f);
    aH.x = fmaxf(fmaf(d, aH.x, b1.x), 0.f);
    aH.y = fmaxf(fmaf(d, aH.y, b1.y), 0.f);
    aH.z = fmaxf(fmaf(d, aH.z, b1.z), 0.f);
    aH.w = fmaxf(fmaf(d, aH.w, b1.w), 0.f);

    if (outp) {
        float4 w0 = ((const float4*)lw)[lane * 2];
        float4 w1 = ((const float4*)lw)[lane * 2 + 1];
        float p = aL.x * w0.x + aL.y * w0.y + aL.z * w0.z + aL.w * w0.w +
                  aH.x * w1.x + aH.y * w1.y + aH.z * w1.z + aH.w * w1.w;
#pragma unroll
        for (int off = 8; off; off >>= 1) p += __shfl_down(p, off);
        if (lane == 0) outp[node] = p + lb[0];
    } else {
        uint4 o;
        o.x = (unsigned int)bf16rne(aL.x) | ((unsigned int)bf16rne(aL.y) << 16);
        o.y = (unsigned int)bf16rne(aL.z) | ((unsigned int)bf16rne(aL.w) << 16);
        o.z = (unsigned int)bf16rne(aH.x) | ((unsigned int)bf16rne(aH.y) << 16);
        o.w = (unsigned int)bf16rne(aH.z) | ((unsigned int)bf16rne(aH.w) << 16);
        ((uint4*)hb)[(size_t)node * 16 + lane] = o;
    }
}

extern "C" void kernel_launch(void* const* d_in, const int* in_sizes, int n_in,
                              void* d_out, int out_size, void* d_ws, size_t ws_size,
                              hipStream_t stream) {
    const float* x   = (const float*)d_in[0];
    const int*   ei  = (const int*)d_in[1];   // int64 in reference -> int32 on device
    const float* ea  = (const float*)d_in[2];
    const float* W1  = (const float*)d_in[3];
    const float* b1  = (const float*)d_in[4];
    const float* W2  = (const float*)d_in[5];
    const float* b2  = (const float*)d_in[6];
    const float* W3  = (const float*)d_in[7];
    const float* b3  = (const float*)d_in[8];
    const float* lw  = (const float*)d_in[9];
    const float* lb  = (const float*)d_in[10];
    float*       out = (float*)d_out;

    const int* row = ei;        // edge_index[0]
    const int* col = ei + NE;   // edge_index[1]

    const int BS = 256;
    int gBinA   = (NE + EPB - 1) / EPB;
    int gGather = (N_NODES + 15) / 16;
    int gGemm   = (N_NODES + 63) / 64;

    // workspace layout (~85 MB), 8B-aligned blocks first:
    //   babuf uint2[NB*BCAP] | sedge uint2[NB*BCAP] | cursor2 uint2[N] |
    //   dinv f[N] | gbcur i[128] | Wt u16[3*16384] | xwb u16[N*C] | hb u16[N*C]
    char* wsb = (char*)d_ws;
    uint2*          babuf   = (uint2*)wsb;          wsb += (size_t)NB * BCAP * 8;
    uint2*          sedge   = (uint2*)wsb;          wsb += (size_t)NB * BCAP * 8;
    uint2*          cursor2 = (uint2*)wsb;          wsb += (size_t)N_NODES * 8;
    float*          dinv    = (float*)wsb;          wsb += (size_t)N_NODES * 4;
    int*            gbcur   = (int*)wsb;            wsb += 128 * 4;
    unsigned short* Wt      = (unsigned short*)wsb; wsb += 3 * 16384 * 2;
    unsigned short* xwb     = (unsigned short*)wsb; wsb += (size_t)N_NODES * C * 2;
    unsigned short* hb      = (unsigned short*)wsb;

    hipMemsetAsync(gbcur, 0, 128 * 4, stream);
    wt3_kernel<<<dim3(64, 3), BS, 0, stream>>>(W1, W2, W3, Wt);
    binA_kernel<<<gBinA, BS, 0, stream>>>(row, col, ea, gbcur, babuf);
    binB_kernel<<<NB, BS, 0, stream>>>(gbcur, babuf, dinv, cursor2, sedge);

    // layer 1 (fp32 input)
    gemm_mfma<<<gGemm, BS, 0, stream>>>(x, nullptr, Wt, dinv, xwb, N_NODES);
    gather_csr<<<gGather, BS, 0, stream>>>(cursor2, sedge, xwb, dinv, b1, hb,
                                           nullptr, nullptr, nullptr);
    // layer 2 (bf16 h input)
    gemm_mfma<<<gGemm, BS, 0, stream>>>(nullptr, hb, Wt + 16384, dinv, xwb, N_NODES);
    gather_csr<<<gGather, BS, 0, stream>>>(cursor2, sedge, xwb, dinv, b2, hb,
                                           nullptr, nullptr, nullptr);
    // layer 3 + fused final linear
    gemm_mfma<<<gGemm, BS, 0, stream>>>(nullptr, hb, Wt + 32768, dinv, xwb, N_NODES);
    gather_csr<<<gGather, BS, 0, stream>>>(cursor2, sedge, xwb, dinv, b3, nullptr,
                                           out, lw, lb);
}

// Round 12
// 416.607 us; speedup vs baseline: 1.1515x; 1.1515x over previous
//
#include <hip/hip_runtime.h>

#define N_NODES 100000
#define NE      1600000
#define C       128
#define NB      98        // buckets of 1024 destination nodes
#define BCAP    20480     // per-bucket capacity; mean 16384, ~32-sigma margin
#define EPB     2048      // edges per binA block

typedef __attribute__((ext_vector_type(8))) short short8;
typedef __attribute__((ext_vector_type(4))) float float4v;

__device__ __forceinline__ unsigned short bf16rne(float f) {
    unsigned int u = __float_as_uint(f);
    return (unsigned short)((u + 0x7FFFu + ((u >> 16) & 1u)) >> 16);
}
__device__ __forceinline__ float blo(unsigned int u) { return __uint_as_float(u << 16); }
__device__ __forceinline__ float bhi(unsigned int u) { return __uint_as_float(u & 0xFFFF0000u); }

// ---- binA: coarse-bucket by c>>10 with LDS-staged coalesced writes --------
__global__ __launch_bounds__(256) void binA_kernel(const int* __restrict__ row,
                                                   const int* __restrict__ col,
                                                   const float* __restrict__ ew,
                                                   int* __restrict__ gbcur,
                                                   uint2* __restrict__ babuf) {
    __shared__ int   hcnt[NB];
    __shared__ int   hofs[NB];
    __shared__ int   hbase[NB];
    __shared__ int   lofs[NB];
    __shared__ uint2 recs[EPB];   // 16 KB
    __shared__ int   gdst[EPB];   // 8 KB
    const int t = threadIdx.x;
    for (int i = t; i < NB; i += 256) { hcnt[i] = 0; hofs[i] = 0; }
    __syncthreads();

    const int e0 = blockIdx.x * EPB;
    int cc[8], rr[8]; float ee[8];
#pragma unroll
    for (int i = 0; i < 8; i++) {
        int e = e0 + i * 256 + t;
        if (e < NE) { cc[i] = col[e]; rr[i] = row[e]; ee[i] = ew[e]; }
        else cc[i] = -1;
    }
#pragma unroll
    for (int i = 0; i < 8; i++)
        if (cc[i] >= 0) atomicAdd(&hcnt[cc[i] >> 10], 1);
    __syncthreads();
    if (t < NB) {
        int c = hcnt[t];
        hbase[t] = c ? atomicAdd(&gbcur[t], c) : 0;
    }
    if (t == 0) {
        int run = 0;
        for (int b = 0; b < NB; b++) { lofs[b] = run; run += hcnt[b]; }
    }
    __syncthreads();
#pragma unroll
    for (int i = 0; i < 8; i++) {
        if (cc[i] < 0) continue;
        int b = cc[i] >> 10;
        int lpos = atomicAdd(&hofs[b], 1);
        int si = lofs[b] + lpos;
        unsigned int meta = ((unsigned int)(cc[i] & 1023) << 17) | (unsigned int)rr[i];
        recs[si] = make_uint2(meta, __float_as_uint(ee[i]));
        int gp = hbase[b] + lpos;
        gdst[si] = (gp < BCAP) ? (b * BCAP + gp) : -1;
    }
    __syncthreads();
    const int valid = lofs[NB - 1] + hcnt[NB - 1];
    for (int i = t; i < valid; i += 256) {
        int g = gdst[i];
        if (g >= 0) babuf[g] = recs[i];
    }
}

// ---- binB: per-bucket histogram + weighted degree + scan + local scatter --
__global__ __launch_bounds__(256) void binB_kernel(const int* __restrict__ gbcur,
                                                   const uint2* __restrict__ babuf,
                                                   float* __restrict__ dinv,
                                                   uint2* __restrict__ cursor2,
                                                   uint2* __restrict__ sedge) {
    __shared__ int   cnt[1024];
    __shared__ float deg[1024];
    __shared__ int   ofs[1024];
    __shared__ int   tsum[256];
    const int b = blockIdx.x, t = threadIdx.x;
    const int n0 = b << 10;
    const int nn = min(1024, N_NODES - n0);

    for (int i = t; i < 1024; i += 256) { cnt[i] = 0; deg[i] = 0.f; }
    __syncthreads();

    const int msize = min(gbcur[b], BCAP);
    const uint2* bb = babuf + (size_t)b * BCAP;
    for (int i = t; i < msize; i += 256) {
        uint2 m = bb[i];
        int cl = m.x >> 17;
        atomicAdd(&cnt[cl], 1);
        atomicAdd(&deg[cl], __uint_as_float(m.y));
    }
    __syncthreads();

    for (int i = t; i < nn; i += 256)
        dinv[n0 + i] = 1.0f / sqrtf(deg[i] + 1.0f);

    const int b4 = t * 4;
    int c0 = cnt[b4], c1 = cnt[b4 + 1], c2 = cnt[b4 + 2], c3 = cnt[b4 + 3];
    tsum[t] = c0 + c1 + c2 + c3;
    __syncthreads();
    for (int off = 1; off < 256; off <<= 1) {
        int v = (t >= off) ? tsum[t - off] : 0;
        __syncthreads();
        tsum[t] += v;
        __syncthreads();
    }
    int texcl = t ? tsum[t - 1] : 0;
    ofs[b4]     = texcl;
    ofs[b4 + 1] = texcl + c0;
    ofs[b4 + 2] = texcl + c0 + c1;
    ofs[b4 + 3] = texcl + c0 + c1 + c2;
    __syncthreads();

    const unsigned int ebase = (unsigned int)b * BCAP;
    for (int i = t; i < nn; i += 256) {
        unsigned int st = ebase + (unsigned int)ofs[i];
        cursor2[n0 + i] = make_uint2(st, st + (unsigned int)cnt[i]);
    }
    __syncthreads();

    for (int i = t; i < msize; i += 256) {
        uint2 m = bb[i];
        int cl = m.x >> 17;
        int p = atomicAdd(&ofs[cl], 1);
        sedge[(size_t)b * BCAP + p] = make_uint2(m.x & 0x1FFFFu, m.y);
    }
}

// ---- Wt[l][n][k] = bf16(Wl[k][n]) for all 3 layers in one dispatch --------
__global__ __launch_bounds__(256) void wt3_kernel(const float* __restrict__ W1,
                                                  const float* __restrict__ W2,
                                                  const float* __restrict__ W3,
                                                  unsigned short* __restrict__ Wt) {
    int layer = blockIdx.y;
    const float* W = layer == 0 ? W1 : (layer == 1 ? W2 : W3);
    int i = blockIdx.x * 256 + threadIdx.x;   // 16384 per layer
    int n = i >> 7, k = i & 127;
    Wt[layer * 16384 + i] = bf16rne(W[k * 128 + n]);
}

// ------- MFMA GEMM, swapped operands: T = bf16( dinv * (X @ W) ) -----------
// A = Wt rows (outcols, staged once in LDS, high reuse); B = X rows (nodes,
// DIRECT coalesced global loads: 16 nodes x 64B full sectors per instr).
// D layout: lane = node, quad*4+reg = 4 consecutive outcols -> uint2 stores.
// Block = 128 nodes (4 waves x 2 node-tiles of 16); W LDS reads amortized 2x.
__global__ __launch_bounds__(256) void gemm_mfma(const float* __restrict__ Xf,
                                                 const unsigned short* __restrict__ Xb,
                                                 const unsigned short* __restrict__ Wt,
                                                 const float* __restrict__ dinv,
                                                 unsigned short* __restrict__ Yb,
                                                 int n) {
    __shared__ unsigned short sW[128 * 136];   // [outcol][k], +8 pad
    const int tid = threadIdx.x;

    // stage Wt: 2048 uint4 (8 per thread)
    for (int i = tid; i < 128 * 16; i += 256) {
        int nr = i >> 4, q = i & 15;
        *(uint4*)&sW[nr * 136 + q * 8] = ((const uint4*)Wt)[i];
    }
    __syncthreads();

    const int wave = tid >> 6, lane = tid & 63;
    const int m = lane & 15, quad = lane >> 4;
    const int node0 = blockIdx.x * 128 + wave * 32;   // wave covers 32 nodes
    const int nodeA = node0 + m;                       // tile 0 node for this lane
    const int nodeB = node0 + 16 + m;                  // tile 1 node

    float4v acc[2][8];
#pragma unroll
    for (int nt = 0; nt < 2; nt++)
#pragma unroll
        for (int t = 0; t < 8; t++) acc[nt][t] = (float4v){0.f, 0.f, 0.f, 0.f};

#pragma unroll
    for (int kc = 0; kc < 4; kc++) {
        const int k0 = kc * 32 + quad * 8;
        short8 xf[2];
#pragma unroll
        for (int nt = 0; nt < 2; nt++) {
            int nd = nt ? nodeB : nodeA;
            short8 v = (short8){0, 0, 0, 0, 0, 0, 0, 0};
            if (nd < n) {
                if (Xf) {
                    float4 f0 = *(const float4*)(Xf + (size_t)nd * 128 + k0);
                    float4 f1 = *(const float4*)(Xf + (size_t)nd * 128 + k0 + 4);
                    v[0] = (short)bf16rne(f0.x); v[1] = (short)bf16rne(f0.y);
                    v[2] = (short)bf16rne(f0.z); v[3] = (short)bf16rne(f0.w);
                    v[4] = (short)bf16rne(f1.x); v[5] = (short)bf16rne(f1.y);
                    v[6] = (short)bf16rne(f1.z); v[7] = (short)bf16rne(f1.w);
                } else {
                    v = *(const short8*)(Xb + (size_t)nd * 128 + k0);
                }
            }
            xf[nt] = v;
        }
#pragma unroll
        for (int t = 0; t < 8; t++) {
            short8 w = *(const short8*)&sW[(t * 16 + m) * 136 + k0];
            acc[0][t] = __builtin_amdgcn_mfma_f32_16x16x32_bf16(w, xf[0], acc[0][t], 0, 0, 0);
            acc[1][t] = __builtin_amdgcn_mfma_f32_16x16x32_bf16(w, xf[1], acc[1][t], 0, 0, 0);
        }
    }

    // epilogue: D[m=outcol][n=node]; lane owns node=tile+m, outcols quad*4+reg
#pragma unroll
    for (int nt = 0; nt < 2; nt++) {
        int nd = nt ? nodeB : nodeA;
        if (nd >= n) continue;
        float dv = dinv[nd];
#pragma unroll
        for (int t = 0; t < 8; t++) {
            uint2 o;
            o.x = (unsigned int)bf16rne(acc[nt][t][0] * dv) |
                  ((unsigned int)bf16rne(acc[nt][t][1] * dv) << 16);
            o.y = (unsigned int)bf16rne(acc[nt][t][2] * dv) |
                  ((unsigned int)bf16rne(acc[nt][t][3] * dv) << 16);
            *(uint2*)&Yb[(size_t)nd * 128 + t * 16 + quad * 4] = o;
        }
    }
}

// -------- CSR gather: h = relu( dinv[c]*(T[c] + sum ew*T[r]) + bias ) ------
// 16 lanes per node (16 nodes/block), 16B dwordx4 per lane per edge.
// If outp != nullptr: fuse final linear (dot with lw, +lb) instead of h.
__global__ __launch_bounds__(256) void gather_csr(const uint2* __restrict__ cursor2,
                                                  const uint2* __restrict__ sedge,
                                                  const unsigned short* __restrict__ xwb,
                                                  const float* __restrict__ dinv,
                                                  const float* __restrict__ bias,
                                                  unsigned short* __restrict__ hb,
                                                  float* __restrict__ outp,
                                                  const float* __restrict__ lw,
                                                  const float* __restrict__ lb) {
    int node = blockIdx.x * 16 + (threadIdx.x >> 4);
    int lane = threadIdx.x & 15;
    if (node >= N_NODES) return;
    uint2 cu = cursor2[node];
    int e = (int)cu.x, end = (int)cu.y;
    const uint4* tab = (const uint4*)xwb;   // 16 uint4 per node row

    uint4 q0 = tab[(size_t)node * 16 + lane];
    float4 aL, aH;
    aL.x = blo(q0.x); aL.y = bhi(q0.x); aL.z = blo(q0.y); aL.w = bhi(q0.y);
    aH.x = blo(q0.z); aH.y = bhi(q0.z); aH.z = blo(q0.w); aH.w = bhi(q0.w);

    for (; e + 4 <= end; e += 4) {
        uint2 E[4]; uint4 q[4];
#pragma unroll
        for (int j = 0; j < 4; j++) E[j] = sedge[e + j];
#pragma unroll
        for (int j = 0; j < 4; j++) q[j] = tab[(size_t)E[j].x * 16 + lane];
#pragma unroll
        for (int j = 0; j < 4; j++) {
            float w = __uint_as_float(E[j].y);
            aL.x += w * blo(q[j].x); aL.y += w * bhi(q[j].x);
            aL.z += w * blo(q[j].y); aL.w += w * bhi(q[j].y);
            aH.x += w * blo(q[j].z); aH.y += w * bhi(q[j].z);
            aH.z += w * blo(q[j].w); aH.w += w * bhi(q[j].w);
        }
    }
    for (; e < end; ++e) {
        uint2 E = sedge[e];
        float w = __uint_as_float(E.y);
        uint4 q = tab[(size_t)E.x * 16 + lane];
        aL.x += w * blo(q.x); aL.y += w * bhi(q.x);
        aL.z += w * blo(q.y); aL.w += w * bhi(q.y);
        aH.x += w * blo(q.z); aH.y += w * bhi(q.z);
        aH.z += w * blo(q.w); aH.w += w * bhi(q.w);
    }

    float d = dinv[node];
    float4 b0 = ((const float4*)bias)[lane * 2];
    float4 b1 = ((const float4*)bias)[lane * 2 + 1];
    aL.x = fmaxf(fmaf(d, aL.x, b0.x), 0.f);
    aL.y = fmaxf(fmaf(d, aL.y, b0.y), 0.f);
    aL.z = fmaxf(fmaf(d, aL.z, b0.z), 0.f);
    aL.w = fmaxf(fmaf(d, aL.w, b0.w), 0.f);
    aH.x = fmaxf(fmaf(d, aH.x, b1.x), 0.f);
    aH.y = fmaxf(fmaf(d, aH.y, b1.y), 0.f);
    aH.z = fmaxf(fmaf(d, aH.z, b1.z), 0.f);
    aH.w = fmaxf(fmaf(d, aH.w, b1.w), 0.f);

    if (outp) {
        float4 w0 = ((const float4*)lw)[lane * 2];
        float4 w1 = ((const float4*)lw)[lane * 2 + 1];
        float p = aL.x * w0.x + aL.y * w0.y + aL.z * w0.z + aL.w * w0.w +
                  aH.x * w1.x + aH.y * w1.y + aH.z * w1.z + aH.w * w1.w;
#pragma unroll
        for (int off = 8; off; off >>= 1) p += __shfl_down(p, off);
        if (lane == 0) outp[node] = p + lb[0];
    } else {
        uint4 o;
        o.x = (unsigned int)bf16rne(aL.x) | ((unsigned int)bf16rne(aL.y) << 16);
        o.y = (unsigned int)bf16rne(aL.z) | ((unsigned int)bf16rne(aL.w) << 16);
        o.z = (unsigned int)bf16rne(aH.x) | ((unsigned int)bf16rne(aH.y) << 16);
        o.w = (unsigned int)bf16rne(aH.z) | ((unsigned int)bf16rne(aH.w) << 16);
        ((uint4*)hb)[(size_t)node * 16 + lane] = o;
    }
}

extern "C" void kernel_launch(void* const* d_in, const int* in_sizes, int n_in,
                              void* d_out, int out_size, void* d_ws, size_t ws_size,
                              hipStream_t stream) {
    const float* x   = (const float*)d_in[0];
    const int*   ei  = (const int*)d_in[1];   // int64 in reference -> int32 on device
    const float* ea  = (const float*)d_in[2];
    const float* W1  = (const float*)d_in[3];
    const float* b1  = (const float*)d_in[4];
    const float* W2  = (const float*)d_in[5];
    const float* b2  = (const float*)d_in[6];
    const float* W3  = (const float*)d_in[7];
    const float* b3  = (const float*)d_in[8];
    const float* lw  = (const float*)d_in[9];
    const float* lb  = (const float*)d_in[10];
    float*       out = (float*)d_out;

    const int* row = ei;        // edge_index[0]
    const int* col = ei + NE;   // edge_index[1]

    const int BS = 256;
    int gBinA   = (NE + EPB - 1) / EPB;
    int gGather = (N_NODES + 15) / 16;
    int gGemm   = (N_NODES + 127) / 128;

    // workspace layout (~85 MB), 8B-aligned blocks first:
    //   babuf uint2[NB*BCAP] | sedge uint2[NB*BCAP] | cursor2 uint2[N] |
    //   dinv f[N] | gbcur i[128] | Wt u16[3*16384] | xwb u16[N*C] | hb u16[N*C]
    char* wsb = (char*)d_ws;
    uint2*          babuf   = (uint2*)wsb;          wsb += (size_t)NB * BCAP * 8;
    uint2*          sedge   = (uint2*)wsb;          wsb += (size_t)NB * BCAP * 8;
    uint2*          cursor2 = (uint2*)wsb;          wsb += (size_t)N_NODES * 8;
    float*          dinv    = (float*)wsb;          wsb += (size_t)N_NODES * 4;
    int*            gbcur   = (int*)wsb;            wsb += 128 * 4;
    unsigned short* Wt      = (unsigned short*)wsb; wsb += 3 * 16384 * 2;
    unsigned short* xwb     = (unsigned short*)wsb; wsb += (size_t)N_NODES * C * 2;
    unsigned short* hb      = (unsigned short*)wsb;

    hipMemsetAsync(gbcur, 0, 128 * 4, stream);
    wt3_kernel<<<dim3(64, 3), BS, 0, stream>>>(W1, W2, W3, Wt);
    binA_kernel<<<gBinA, BS, 0, stream>>>(row, col, ea, gbcur, babuf);
    binB_kernel<<<NB, BS, 0, stream>>>(gbcur, babuf, dinv, cursor2, sedge);

    // layer 1 (fp32 input)
    gemm_mfma<<<gGemm, BS, 0, stream>>>(x, nullptr, Wt, dinv, xwb, N_NODES);
    gather_csr<<<gGather, BS, 0, stream>>>(cursor2, sedge, xwb, dinv, b1, hb,
                                           nullptr, nullptr, nullptr);
    // layer 2 (bf16 h input)
    gemm_mfma<<<gGemm, BS, 0, stream>>>(nullptr, hb, Wt + 16384, dinv, xwb, N_NODES);
    gather_csr<<<gGather, BS, 0, stream>>>(cursor2, sedge, xwb, dinv, b2, hb,
                                           nullptr, nullptr, nullptr);
    // layer 3 + fused final linear
    gemm_mfma<<<gGemm, BS, 0, stream>>>(nullptr, hb, Wt + 32768, dinv, xwb, N_NODES);
    gather_csr<<<gGather, BS, 0, stream>>>(cursor2, sedge, xwb, dinv, b3, nullptr,
                                           out, lw, lb);
}